// Round 19
// baseline (166.927 us; speedup 1.0000x reference)
//
#include <hip/hip_runtime.h>

#define NN 4096
#define DD 512
#define HH 8
#define DHH 64

typedef __attribute__((ext_vector_type(8))) __bf16 bfrag;
typedef __attribute__((ext_vector_type(8))) short short8;
typedef __attribute__((ext_vector_type(8))) unsigned short ushort8v;
typedef __attribute__((ext_vector_type(4))) float f32x4;
typedef unsigned int uint32;

// async global->LDS, 16B per lane. LDS dest is wave-uniform base + lane*16.
#define GLOAD16(gp, lp)                                                        \
    __builtin_amdgcn_global_load_lds(                                          \
        (const __attribute__((address_space(1))) unsigned int*)(gp),           \
        (__attribute__((address_space(3))) unsigned int*)(lp), 16, 0, 0)

// counted vmcnt wait (literal immediates only)
template <int N>
__device__ __forceinline__ void waitcnt_vm() {
    if constexpr (N == 0) asm volatile("s_waitcnt vmcnt(0)" ::: "memory");
    else if constexpr (N == 4) asm volatile("s_waitcnt vmcnt(4)" ::: "memory");
    else if constexpr (N == 6) asm volatile("s_waitcnt vmcnt(6)" ::: "memory");
    else if constexpr (N == 8) asm volatile("s_waitcnt vmcnt(8)" ::: "memory");
    else if constexpr (N == 12) asm volatile("s_waitcnt vmcnt(12)" ::: "memory");
    else static_assert(N == 0, "unsupported vmcnt literal");
}

// f32 -> bf16 round-to-nearest-even
__device__ __forceinline__ unsigned short f2b(float f) {
    unsigned int u = __builtin_bit_cast(unsigned int, f);
    unsigned int r = 0x7fffu + ((u >> 16) & 1u);
    return (unsigned short)((u + r) >> 16);
}

__device__ __forceinline__ float b2f(unsigned short u) {
    return __builtin_bit_cast(float, (unsigned int)u << 16);
}

__device__ __forceinline__ float fexp2(float x) {
#if __has_builtin(__builtin_amdgcn_exp2f)
    return __builtin_amdgcn_exp2f(x);
#else
    return exp2f(x);
#endif
}

__device__ __forceinline__ void load_edge(const void* ei, int E, int i, int is32,
                                          int& r, int& c) {
    if (is32) {
        const int* p = (const int*)ei;
        r = p[i]; c = p[E + i];
    } else {
        const long long* p = (const long long*)ei;
        r = (int)p[i]; c = (int)p[E + i];
    }
}

// ---------------- layernorm: one wave per row, no LDS / no syncthreads -------
__device__ __forceinline__ void ln_row_wave(const float* __restrict__ x,
                                            const float* __restrict__ w,
                                            const float* __restrict__ b,
                                            unsigned short* __restrict__ out,
                                            int row, int lane) {
    const float4* xp = reinterpret_cast<const float4*>(x + (size_t)row * DD + lane * 8);
    const float4 v0 = xp[0], v1 = xp[1];
    float s  = (v0.x + v0.y) + (v0.z + v0.w) + (v1.x + v1.y) + (v1.z + v1.w);
    float s2 = v0.x * v0.x + v0.y * v0.y + v0.z * v0.z + v0.w * v0.w +
               v1.x * v1.x + v1.y * v1.y + v1.z * v1.z + v1.w * v1.w;
#pragma unroll
    for (int d = 1; d < 64; d <<= 1) {
        s += __shfl_xor(s, d);
        s2 += __shfl_xor(s2, d);
    }
    const float mean = s * (1.f / DD);
    const float var = fmaxf(s2 * (1.f / DD) - mean * mean, 0.f);
    const float rs = rsqrtf(var + 1e-5f);
    const float4* wp = reinterpret_cast<const float4*>(w + lane * 8);
    const float4* bp = reinterpret_cast<const float4*>(b + lane * 8);
    const float4 w0 = wp[0], w1 = wp[1], b0 = bp[0], b1 = bp[1];
    ushort8v o;
    o[0] = f2b((v0.x - mean) * rs * w0.x + b0.x);
    o[1] = f2b((v0.y - mean) * rs * w0.y + b0.y);
    o[2] = f2b((v0.z - mean) * rs * w0.z + b0.z);
    o[3] = f2b((v0.w - mean) * rs * w0.w + b0.w);
    o[4] = f2b((v1.x - mean) * rs * w1.x + b1.x);
    o[5] = f2b((v1.y - mean) * rs * w1.y + b1.y);
    o[6] = f2b((v1.z - mean) * rs * w1.z + b1.z);
    o[7] = f2b((v1.w - mean) * rs * w1.w + b1.w);
    *reinterpret_cast<ushort8v*>(out + (size_t)row * DD + lane * 8) = o;
}

// ---------------- fused prologue: weight cvt + LN1 + mask/counter zero -------
#define W_IN_N 786432
#define W_OUT_N 262144
#define W1_N 1048576
#define W2_N 1048576
#define CVT_BLKS 3072
#define LN_BLKS 1024
#define ZERO_BLKS 32
__global__ __launch_bounds__(256) void prologue(
    const float* __restrict__ w_in, const float* __restrict__ w_out,
    const float* __restrict__ w1, const float* __restrict__ w2,
    unsigned short* __restrict__ o_in, unsigned short* __restrict__ o_out,
    unsigned short* __restrict__ o1, unsigned short* __restrict__ o2,
    const float* __restrict__ x, const float* __restrict__ ln1w,
    const float* __restrict__ ln1b, unsigned short* __restrict__ xn,
    uint32* __restrict__ mask, uint32* __restrict__ row_cnt) {
    const int bb = blockIdx.x;
    if (bb < CVT_BLKS) {
        int idx = (bb * 256 + threadIdx.x) * 4;
        const float* src;
        unsigned short* dst;
        int off;
        if (idx < W_IN_N) { src = w_in; dst = o_in; off = idx; }
        else if (idx < W_IN_N + W_OUT_N) { src = w_out; dst = o_out; off = idx - W_IN_N; }
        else if (idx < W_IN_N + W_OUT_N + W1_N) { src = w1; dst = o1; off = idx - (W_IN_N + W_OUT_N); }
        else { src = w2; dst = o2; off = idx - (W_IN_N + W_OUT_N + W1_N); }
        float4 v = *reinterpret_cast<const float4*>(src + off);
        ushort4 o;
        o.x = f2b(v.x); o.y = f2b(v.y); o.z = f2b(v.z); o.w = f2b(v.w);
        *reinterpret_cast<ushort4*>(dst + off) = o;
    } else if (bb < CVT_BLKS + LN_BLKS) {
        ln_row_wave(x, ln1w, ln1b, xn,
                    (bb - CVT_BLKS) * 4 + (threadIdx.x >> 6), threadIdx.x & 63);
    } else {
        // zero the 2 MiB adjacency bitmask (+ the 64 row-fan-in counters)
        const int z = bb - (CVT_BLKS + LN_BLKS);
        uint4 zero4 = {0u, 0u, 0u, 0u};
        uint4* mp = reinterpret_cast<uint4*>(mask);
#pragma unroll
        for (int i = 0; i < 16; ++i)
            mp[(size_t)z * 4096 + i * 256 + threadIdx.x] = zero4;
        if (z == 0 && threadIdx.x < 64) row_cnt[threadIdx.x] = 0u;
    }
}

// ---------------- bf16 MFMA GEMM, tile BM x BN, 2-deep pipeline --------------
// K-loop: double-buffered gload_lds staging (pre-swizzled global source chunk
// + XOR-swizzled ds_read => conflict-free), counted vmcnt (never 0 mid-loop)
// + raw s_barrier. XCD swizzle: tm = wgid % (NN/BM) (NN/BM multiple of 8).
// Epilogue: acc(+bias) bounced through LDS -> contiguous 16B global stores.
// EPI 0: QKV -> q (bf16, scaled)/k/v, [N][512] bf16; also folds the adjacency
//        bitmask build (atomicOr of edges + diagonal) before staging — its
//        vmem ops retire before the first counted vmcnt wait (in-order count).
// EPI 1: out_f = acc + bias + resid (f32); if row_cnt != nullptr, the last
//        col-block of each row-tile (fan-in counter) runs LN2 for its rows
//        (all 8 writers share one XCD: wgid ≡ tm mod 64 ⇒ same mod-8 class).
// EPI 2: out_b = bf16(relu(acc + bias)), row stride 2048
template <int BM, int BN, int EPI>
__global__ __launch_bounds__(256) void gemm_swz(const unsigned short* __restrict__ A,
                                                const unsigned short* __restrict__ B,
                                                int K,
                                                const float* __restrict__ bias,
                                                const float* __restrict__ resid,
                                                float* __restrict__ out_f,
                                                unsigned short* __restrict__ out_b,
                                                unsigned short* __restrict__ q_out,
                                                unsigned short* __restrict__ k_out,
                                                unsigned short* __restrict__ v_out,
                                                const void* __restrict__ ei,
                                                uint32* __restrict__ mask, int E,
                                                const float* __restrict__ ln2w,
                                                const float* __restrict__ ln2b,
                                                unsigned short* __restrict__ xm_out,
                                                uint32* __restrict__ row_cnt) {
    constexpr int MR = BM / 32;          // fragments per wave (M)
    constexpr int NR = BN / 32;          // fragments per wave (N)
    constexpr int LA = BM / 32;          // A gloads per wave per tile
    constexpr int LB = BN / 32;          // B gloads per wave per tile
    constexpr int CSTR = BN + 4;         // f32 bounce stride (16B-aligned rows)
    constexpr size_t PIPE_B = (size_t)2 * (BM + BN) * 64 * 2;
    constexpr size_t EPI_B = (size_t)BM * CSTR * 4;
    constexpr size_t LDS_B = PIPE_B > EPI_B ? PIPE_B : EPI_B;
    __shared__ __align__(16) unsigned char smem[LDS_B];
    unsigned short* a_lds = (unsigned short*)smem;
    unsigned short* b_lds = a_lds + (size_t)2 * BM * 64;
    float* c_lds = (float*)smem;

    const int tid = threadIdx.x;
    const int lane = tid & 63;
    const int wave = tid >> 6;
    const int wm = wave >> 1, wn = wave & 1;
    const int wgid = blockIdx.x;
    const int tm = wgid % (NN / BM);
    const int tn = wgid / (NN / BM);

    // ---- folded adjacency build (QKV only): self-draining, before staging ----
    if constexpr (EPI == 0) {
        if (mask) {
            const int odd = ((const int*)ei)[2 * lane + 1];
            const int is32 = (__ballot(odd != 0) != 0ull) ? 1 : 0;
            const int total = E + NN;
            for (int i = wgid * 256 + tid; i < total; i += (int)gridDim.x * 256) {
                int r, c;
                if (i < E) load_edge(ei, E, i, is32, r, c);
                else { r = i - E; c = r; }
                atomicOr(&mask[r * 128 + (c >> 5)], 1u << (c & 31));
            }
        }
    }

    f32x4 acc[MR][NR];
#pragma unroll
    for (int mi = 0; mi < MR; ++mi)
#pragma unroll
        for (int ni = 0; ni < NR; ++ni) acc[mi][ni] = (f32x4){0.f, 0.f, 0.f, 0.f};

    // staging: chunk = 1KB = 8 rows x 64 cols; lane covers row = chunk*8+l/8,
    // global col-chunk = (l&7)^(l>>3) (inverse swizzle), LDS dest linear l*16.
    const int srow = lane >> 3;
    const int sswz = ((lane & 7) ^ srow) << 3;
    const unsigned short* a_src = A + (size_t)(tm * BM + srow) * K + sswz;
    const unsigned short* b_src = B + (size_t)(tn * BN + srow) * K + sswz;

    auto stage = [&](int k0, int buf) {
        unsigned short* al = a_lds + buf * (BM * 64);
        unsigned short* bl = b_lds + buf * (BN * 64);
#pragma unroll
        for (int i = 0; i < LA; ++i) {
            const int c = wave * LA + i;
            GLOAD16(a_src + (size_t)c * 8 * K + k0, al + c * 512);
        }
#pragma unroll
        for (int i = 0; i < LB; ++i) {
            const int c = wave * LB + i;
            GLOAD16(b_src + (size_t)c * 8 * K + k0, bl + c * 512);
        }
    };

    const int NT = K >> 6;
    stage(0, 0);
    for (int t = 0; t < NT; ++t) {
        const int cur = t & 1;
        if (t + 1 < NT) {
            stage((t + 1) << 6, cur ^ 1);   // prefetch next tile
            waitcnt_vm<LA + LB>();          // oldest batch (buf[cur]) landed
        } else {
            waitcnt_vm<0>();
        }
        __builtin_amdgcn_s_barrier();       // all waves staged buf[cur]
        asm volatile("" ::: "memory");
        const unsigned short* al = a_lds + cur * (BM * 64);
        const unsigned short* bl = b_lds + cur * (BN * 64);
#pragma unroll
        for (int ks = 0; ks < 2; ++ks) {
            // fragment col-chunk, XOR-swizzled by row&7 (= lane&7, mi-uniform)
            const int cswz = (((lane >> 4) + ks * 4) ^ (lane & 7)) << 3;
            const int rl = lane & 15;
            bfrag af[MR], bfr[NR];
#pragma unroll
            for (int mi = 0; mi < MR; ++mi)
                af[mi] = *reinterpret_cast<const bfrag*>(
                    &al[(wm * (BM / 2) + mi * 16 + rl) * 64 + cswz]);
#pragma unroll
            for (int ni = 0; ni < NR; ++ni)
                bfr[ni] = *reinterpret_cast<const bfrag*>(
                    &bl[(wn * (BN / 2) + ni * 16 + rl) * 64 + cswz]);
#pragma unroll
            for (int mi = 0; mi < MR; ++mi)
#pragma unroll
                for (int ni = 0; ni < NR; ++ni)
                    acc[mi][ni] = __builtin_amdgcn_mfma_f32_16x16x32_bf16(
                        af[mi], bfr[ni], acc[mi][ni], 0, 0, 0);
        }
        asm volatile("" ::: "memory");
        __builtin_amdgcn_s_barrier();       // all waves done reading buf[cur]
    }

    // ---- epilogue: bounce acc(+bias) through LDS, contiguous 16B stores ----
    __syncthreads();                        // pipeline LDS fully consumed
    {
        const int r0 = (lane >> 4) << 2;
        const int cl = lane & 15;
        float bias_r[NR];
#pragma unroll
        for (int ni = 0; ni < NR; ++ni)
            bias_r[ni] = bias[tn * BN + wn * (BN / 2) + ni * 16 + cl];
#pragma unroll
        for (int mi = 0; mi < MR; ++mi)
#pragma unroll
            for (int ni = 0; ni < NR; ++ni) {
                const int row_l = wm * (BM / 2) + mi * 16 + r0;
                const int col_l = wn * (BN / 2) + ni * 16 + cl;
#pragma unroll
                for (int r = 0; r < 4; ++r)
                    c_lds[(size_t)(row_l + r) * CSTR + col_l] =
                        acc[mi][ni][r] + bias_r[ni];
            }
    }
    __syncthreads();

    if constexpr (EPI == 1) {               // f32 out + resid
        constexpr int IT = (BM * BN) / 1024;
#pragma unroll
        for (int it = 0; it < IT; ++it) {
            const int seg = tid + it * 256;
            const int row = seg / (BN / 4);
            const int c4 = (seg % (BN / 4)) * 4;
            f32x4 v = *reinterpret_cast<const f32x4*>(&c_lds[(size_t)row * CSTR + c4]);
            const size_t gidx = (size_t)(tm * BM + row) * 512 + tn * BN + c4;
            f32x4 rs = *reinterpret_cast<const f32x4*>(&resid[gidx]);
            *reinterpret_cast<f32x4*>(&out_f[gidx]) = v + rs;
        }
        // ---- fused LN2 fan-in: last col-block of this row-tile runs LN2 ----
        if (row_cnt) {
            constexpr int NCOL = 512 / BN;  // col-tiles per row-tile
            __shared__ int s_last;
            __threadfence();                // my x1 stores -> device visible
            __syncthreads();                // whole block's stores done
            if (tid == 0) {
                uint32 old = atomicAdd(&row_cnt[tm], 1u);
                s_last = (old == NCOL - 1);
            }
            __syncthreads();
            if (s_last) {
                __threadfence();            // acquire: drop stale cache lines
                for (int r = wave; r < BM; r += 4)
                    ln_row_wave(out_f, ln2w, ln2b, xm_out, tm * BM + r, lane);
            }
        }
    } else {                                // bf16 out (EPI 0 or 2)
        constexpr int IT = (BM * BN) / 2048;
        unsigned short* dst;
        int cbase, stride;
        float scl = 1.f;
        if constexpr (EPI == 0) {
            const int gc0 = tn * BN;
            const int region = gc0 >> 9;    // 0=q, 1=k, 2=v (block-uniform)
            dst = region == 0 ? q_out : (region == 1 ? k_out : v_out);
            cbase = gc0 - region * 512;
            stride = 512;
            if (region == 0) scl = 0.18033688011112042f;  // 1/8 * log2(e)
        } else {
            dst = out_b;
            cbase = tn * BN;
            stride = 2048;
        }
#pragma unroll
        for (int it = 0; it < IT; ++it) {
            const int seg = tid + it * 256;
            const int row = seg / (BN / 8);
            const int c8 = (seg % (BN / 8)) * 8;
            f32x4 v0 = *reinterpret_cast<const f32x4*>(&c_lds[(size_t)row * CSTR + c8]);
            f32x4 v1 = *reinterpret_cast<const f32x4*>(&c_lds[(size_t)row * CSTR + c8 + 4]);
            ushort8v o;
            if constexpr (EPI == 0) {
#pragma unroll
                for (int i = 0; i < 4; ++i) o[i] = f2b(v0[i] * scl);
#pragma unroll
                for (int i = 0; i < 4; ++i) o[4 + i] = f2b(v1[i] * scl);
            } else {
#pragma unroll
                for (int i = 0; i < 4; ++i) o[i] = f2b(fmaxf(v0[i], 0.f));
#pragma unroll
                for (int i = 0; i < 4; ++i) o[4 + i] = f2b(fmaxf(v1[i], 0.f));
            }
            *reinterpret_cast<ushort8v*>(
                dst + (size_t)(tm * BM + row) * stride + cbase + c8) = o;
        }
    }
}

// ---------------- sparse masked attention: bitmask -> LDS compaction ---------
// wave per query; all 8 heads fused (lane = (h, t), h=lane>>3, t=lane&7).
__global__ __launch_bounds__(256) void attn_sparse(const unsigned short* __restrict__ qb,
                                                   const unsigned short* __restrict__ kb,
                                                   const unsigned short* __restrict__ vb,
                                                   const uint32* __restrict__ mask,
                                                   unsigned short* __restrict__ o_buf) {
    __shared__ int s_cols[4][1024];
    __shared__ int s_cnt[4];
    const int lane = threadIdx.x & 63;
    const int wid = threadIdx.x >> 6;
    const int q = blockIdx.x * 4 + wid;

    if (lane == 0) s_cnt[wid] = 0;
    uint32 w0 = mask[q * 128 + lane];
    uint32 w1 = mask[q * 128 + 64 + lane];
    const int base0 = lane * 32, base1 = (64 + lane) * 32;
    while (w0) {
        int b = __builtin_ctz(w0);
        w0 &= w0 - 1;
        int pos = atomicAdd(&s_cnt[wid], 1);
        s_cols[wid][pos & 1023] = base0 + b;
    }
    while (w1) {
        int b = __builtin_ctz(w1);
        w1 &= w1 - 1;
        int pos = atomicAdd(&s_cnt[wid], 1);
        s_cols[wid][pos & 1023] = base1 + b;
    }
    const int cnt = min(s_cnt[wid], 1024);   // wave-local; DS ops in-order

    ushort8v q8 = *reinterpret_cast<const ushort8v*>(qb + (size_t)q * DD + lane * 8);
    float qf[8];
#pragma unroll
    for (int i = 0; i < 8; ++i) qf[i] = b2f(q8[i]);

    float m_run = -3.0e38f, l_run = 0.f;
    float oa[8];
#pragma unroll
    for (int i = 0; i < 8; ++i) oa[i] = 0.f;

    for (int j0 = 0; j0 < cnt; j0 += 8) {
        float s_arr[8];
        int col_arr[8];
        // ---- pass 1: scores for 8 neighbors (8 independent 1KB gathers) ----
#pragma unroll
        for (int u = 0; u < 8; ++u) {
            const int idx = j0 + u;
            const bool act = idx < cnt;
            const int col = s_cols[wid][act ? idx : 0];   // uniform -> broadcast
            col_arr[u] = col;
            ushort8v kq = *reinterpret_cast<const ushort8v*>(
                kb + (size_t)col * DD + lane * 8);
            float d = qf[0] * b2f(kq[0]);
            d = fmaf(qf[1], b2f(kq[1]), d);
            d = fmaf(qf[2], b2f(kq[2]), d);
            d = fmaf(qf[3], b2f(kq[3]), d);
            d = fmaf(qf[4], b2f(kq[4]), d);
            d = fmaf(qf[5], b2f(kq[5]), d);
            d = fmaf(qf[6], b2f(kq[6]), d);
            d = fmaf(qf[7], b2f(kq[7]), d);
            // reduce across the 8 lanes of this head
            d += __shfl_xor(d, 1);
            d += __shfl_xor(d, 2);
            d += __shfl_xor(d, 4);
            s_arr[u] = act ? d : -3.0e38f;
        }
        float mloc = fmaxf(fmaxf(fmaxf(s_arr[0], s_arr[1]), fmaxf(s_arr[2], s_arr[3])),
                           fmaxf(fmaxf(s_arr[4], s_arr[5]), fmaxf(s_arr[6], s_arr[7])));
        if (mloc > m_run) {                 // defer-rescale: alpha==1 otherwise
            const float alpha = fexp2(m_run - mloc);
            l_run *= alpha;
#pragma unroll
            for (int i = 0; i < 8; ++i) oa[i] *= alpha;
            m_run = mloc;
        }
        // ---- pass 2: exp + PV (no shuffles) ----
#pragma unroll
        for (int u = 0; u < 8; ++u) {
            const float p = fexp2(s_arr[u] - m_run);  // inactive -> 0
            l_run += p;
            ushort8v vq = *reinterpret_cast<const ushort8v*>(
                vb + (size_t)col_arr[u] * DD + lane * 8);
#pragma unroll
            for (int i = 0; i < 8; ++i) oa[i] = fmaf(p, b2f(vq[i]), oa[i]);
        }
    }

    const float rl = 1.f / l_run;
    ushort8v ov;
#pragma unroll
    for (int i = 0; i < 8; ++i) ov[i] = f2b(oa[i] * rl);
    *reinterpret_cast<ushort8v*>(o_buf + (size_t)q * DD + lane * 8) = ov;
}

// ---------------- launch ----------------
extern "C" void kernel_launch(void* const* d_in, const int* in_sizes, int n_in,
                              void* d_out, int out_size, void* d_ws, size_t ws_size,
                              hipStream_t stream) {
    const float* x = (const float*)d_in[0];
    const void* ei = d_in[1];
    const float* ln1w = (const float*)d_in[2];
    const float* ln1b = (const float*)d_in[3];
    const float* w_in = (const float*)d_in[4];
    const float* b_in = (const float*)d_in[5];
    const float* w_out = (const float*)d_in[6];
    const float* b_out = (const float*)d_in[7];
    const float* ln2w = (const float*)d_in[8];
    const float* ln2b = (const float*)d_in[9];
    const float* w1 = (const float*)d_in[10];
    const float* b1 = (const float*)d_in[11];
    const float* w2 = (const float*)d_in[12];
    const float* b2 = (const float*)d_in[13];
    float* out = (float*)d_out;
    const int E = in_sizes[1] / 2;

    char* ws = (char*)d_ws;
    size_t off = 0;
    auto alloc = [&](size_t bytes) -> void* {
        void* p = ws + off;
        off = (off + bytes + 255) & ~(size_t)255;
        return p;
    };
    uint32* mask1 = (uint32*)alloc((size_t)NN * 128 * 4);   // 2 MiB
    uint32* row_cnt = (uint32*)alloc(64 * 4);
    unsigned short* w_in_b = (unsigned short*)alloc((size_t)1536 * 512 * 2);
    unsigned short* w_out_b = (unsigned short*)alloc((size_t)512 * 512 * 2);
    unsigned short* w1_b = (unsigned short*)alloc((size_t)2048 * 512 * 2);
    unsigned short* w2_b = (unsigned short*)alloc((size_t)512 * 2048 * 2);
    unsigned short* xn = (unsigned short*)alloc((size_t)NN * DD * 2);
    unsigned short* q_b = (unsigned short*)alloc((size_t)NN * DD * 2); // 4 MiB
    unsigned short* k_b = (unsigned short*)alloc((size_t)NN * DD * 2); // 4 MiB
    unsigned short* v_b = (unsigned short*)alloc((size_t)NN * DD * 2); // 4 MiB
    unsigned short* o_buf = (unsigned short*)alloc((size_t)NN * DD * 2); // 4 MiB
    float* x1 = (float*)alloc((size_t)NN * DD * 4);
    unsigned short* xm = (unsigned short*)alloc((size_t)NN * DD * 2);
    // MLP hidden [4096][2048] bf16 (16 MiB) aliases q_b+k_b+v_b+o_buf
    // (all dead after out-proj; sizes are 256B-aligned so the span is exact)
    unsigned short* h_buf = q_b;

    // D1: prologue — weight cvt + LN1 (wave/row) + mask/counter zero
    prologue<<<CVT_BLKS + LN_BLKS + ZERO_BLKS, 256, 0, stream>>>(
        w_in, w_out, w1, w2, w_in_b, w_out_b, w1_b, w2_b,
        x, ln1w, ln1b, xn, mask1, row_cnt);

    // D2: QKV GEMM (128x64, grid 768) + folded adjacency-bitmask build
    gemm_swz<128, 64, 0><<<32 * 24, 256, 0, stream>>>(
        xn, w_in_b, 512, b_in, nullptr, nullptr, nullptr, q_b, k_b, v_b,
        ei, mask1, E, nullptr, nullptr, nullptr, nullptr);

    // D3: attention
    attn_sparse<<<NN / 4, 256, 0, stream>>>(q_b, k_b, v_b, mask1, o_buf);

    // D4: out-proj (64x64, grid 512): x1 = x + o @ w_out^T + b_out,
    //     + fused LN2 via per-row-tile fan-in (last of 8 col-blocks)
    gemm_swz<64, 64, 1><<<64 * 8, 256, 0, stream>>>(
        o_buf, w_out_b, 512, b_out, x, x1, nullptr, nullptr, nullptr, nullptr,
        nullptr, nullptr, 0, ln2w, ln2b, xm, row_cnt);

    // D5: MLP1 (128x128, grid 512): h = bf16(relu(xm @ w1^T + b1))
    gemm_swz<128, 128, 2><<<32 * 16, 256, 0, stream>>>(
        xm, w1_b, 512, b1, nullptr, nullptr, h_buf, nullptr, nullptr, nullptr,
        nullptr, nullptr, 0, nullptr, nullptr, nullptr, nullptr);

    // D6: MLP2 (64x64, grid 512): out = x1 + h @ w2^T + b2
    gemm_swz<64, 64, 1><<<64 * 8, 256, 0, stream>>>(
        h_buf, w2_b, 2048, b2, x1, out, nullptr, nullptr, nullptr, nullptr,
        nullptr, nullptr, 0, nullptr, nullptr, nullptr, nullptr);
}

// Round 20
// 92.758 us; speedup vs baseline: 1.7996x; 1.7996x over previous
//
#include <hip/hip_runtime.h>

#define NN 4096
#define DD 512
#define HH 8
#define DHH 64

typedef __attribute__((ext_vector_type(8))) __bf16 bfrag;
typedef __attribute__((ext_vector_type(8))) short short8;
typedef __attribute__((ext_vector_type(8))) unsigned short ushort8v;
typedef __attribute__((ext_vector_type(4))) float f32x4;
typedef unsigned int uint32;

// async global->LDS, 16B per lane. LDS dest is wave-uniform base + lane*16.
#define GLOAD16(gp, lp)                                                        \
    __builtin_amdgcn_global_load_lds(                                          \
        (const __attribute__((address_space(1))) unsigned int*)(gp),           \
        (__attribute__((address_space(3))) unsigned int*)(lp), 16, 0, 0)

// counted vmcnt wait (literal immediates only)
template <int N>
__device__ __forceinline__ void waitcnt_vm() {
    if constexpr (N == 0) asm volatile("s_waitcnt vmcnt(0)" ::: "memory");
    else if constexpr (N == 4) asm volatile("s_waitcnt vmcnt(4)" ::: "memory");
    else if constexpr (N == 6) asm volatile("s_waitcnt vmcnt(6)" ::: "memory");
    else if constexpr (N == 8) asm volatile("s_waitcnt vmcnt(8)" ::: "memory");
    else if constexpr (N == 12) asm volatile("s_waitcnt vmcnt(12)" ::: "memory");
    else static_assert(N == 0, "unsupported vmcnt literal");
}

// f32 -> bf16 round-to-nearest-even
__device__ __forceinline__ unsigned short f2b(float f) {
    unsigned int u = __builtin_bit_cast(unsigned int, f);
    unsigned int r = 0x7fffu + ((u >> 16) & 1u);
    return (unsigned short)((u + r) >> 16);
}

__device__ __forceinline__ float b2f(unsigned short u) {
    return __builtin_bit_cast(float, (unsigned int)u << 16);
}

__device__ __forceinline__ float fexp2(float x) {
#if __has_builtin(__builtin_amdgcn_exp2f)
    return __builtin_amdgcn_exp2f(x);
#else
    return exp2f(x);
#endif
}

__device__ __forceinline__ void load_edge(const void* ei, int E, int i, int is32,
                                          int& r, int& c) {
    if (is32) {
        const int* p = (const int*)ei;
        r = p[i]; c = p[E + i];
    } else {
        const long long* p = (const long long*)ei;
        r = (int)p[i]; c = (int)p[E + i];
    }
}

// ---------------- layernorm: one wave per row, no LDS / no syncthreads -------
__device__ __forceinline__ void ln_row_wave(const float* __restrict__ x,
                                            const float* __restrict__ w,
                                            const float* __restrict__ b,
                                            unsigned short* __restrict__ out,
                                            int row, int lane) {
    const float4* xp = reinterpret_cast<const float4*>(x + (size_t)row * DD + lane * 8);
    const float4 v0 = xp[0], v1 = xp[1];
    float s  = (v0.x + v0.y) + (v0.z + v0.w) + (v1.x + v1.y) + (v1.z + v1.w);
    float s2 = v0.x * v0.x + v0.y * v0.y + v0.z * v0.z + v0.w * v0.w +
               v1.x * v1.x + v1.y * v1.y + v1.z * v1.z + v1.w * v1.w;
#pragma unroll
    for (int d = 1; d < 64; d <<= 1) {
        s += __shfl_xor(s, d);
        s2 += __shfl_xor(s2, d);
    }
    const float mean = s * (1.f / DD);
    const float var = fmaxf(s2 * (1.f / DD) - mean * mean, 0.f);
    const float rs = rsqrtf(var + 1e-5f);
    const float4* wp = reinterpret_cast<const float4*>(w + lane * 8);
    const float4* bp = reinterpret_cast<const float4*>(b + lane * 8);
    const float4 w0 = wp[0], w1 = wp[1], b0 = bp[0], b1 = bp[1];
    ushort8v o;
    o[0] = f2b((v0.x - mean) * rs * w0.x + b0.x);
    o[1] = f2b((v0.y - mean) * rs * w0.y + b0.y);
    o[2] = f2b((v0.z - mean) * rs * w0.z + b0.z);
    o[3] = f2b((v0.w - mean) * rs * w0.w + b0.w);
    o[4] = f2b((v1.x - mean) * rs * w1.x + b1.x);
    o[5] = f2b((v1.y - mean) * rs * w1.y + b1.y);
    o[6] = f2b((v1.z - mean) * rs * w1.z + b1.z);
    o[7] = f2b((v1.w - mean) * rs * w1.w + b1.w);
    *reinterpret_cast<ushort8v*>(out + (size_t)row * DD + lane * 8) = o;
}

__global__ __launch_bounds__(256) void ln_rows(const float* __restrict__ x,
                                               const float* __restrict__ w,
                                               const float* __restrict__ b,
                                               unsigned short* __restrict__ out) {
    ln_row_wave(x, w, b, out, blockIdx.x * 4 + (threadIdx.x >> 6), threadIdx.x & 63);
}

// ---------------- fused prologue: weight cvt + LN1 + mask zero ---------------
#define W_IN_N 786432
#define W_OUT_N 262144
#define W1_N 1048576
#define W2_N 1048576
#define CVT_BLKS 3072
#define LN_BLKS 1024
#define ZERO_BLKS 32
__global__ __launch_bounds__(256) void prologue(
    const float* __restrict__ w_in, const float* __restrict__ w_out,
    const float* __restrict__ w1, const float* __restrict__ w2,
    unsigned short* __restrict__ o_in, unsigned short* __restrict__ o_out,
    unsigned short* __restrict__ o1, unsigned short* __restrict__ o2,
    const float* __restrict__ x, const float* __restrict__ ln1w,
    const float* __restrict__ ln1b, unsigned short* __restrict__ xn,
    uint32* __restrict__ mask) {
    const int bb = blockIdx.x;
    if (bb < CVT_BLKS) {
        int idx = (bb * 256 + threadIdx.x) * 4;
        const float* src;
        unsigned short* dst;
        int off;
        if (idx < W_IN_N) { src = w_in; dst = o_in; off = idx; }
        else if (idx < W_IN_N + W_OUT_N) { src = w_out; dst = o_out; off = idx - W_IN_N; }
        else if (idx < W_IN_N + W_OUT_N + W1_N) { src = w1; dst = o1; off = idx - (W_IN_N + W_OUT_N); }
        else { src = w2; dst = o2; off = idx - (W_IN_N + W_OUT_N + W1_N); }
        float4 v = *reinterpret_cast<const float4*>(src + off);
        ushort4 o;
        o.x = f2b(v.x); o.y = f2b(v.y); o.z = f2b(v.z); o.w = f2b(v.w);
        *reinterpret_cast<ushort4*>(dst + off) = o;
    } else if (bb < CVT_BLKS + LN_BLKS) {
        ln_row_wave(x, ln1w, ln1b, xn,
                    (bb - CVT_BLKS) * 4 + (threadIdx.x >> 6), threadIdx.x & 63);
    } else {
        // zero the 2 MiB adjacency bitmask (32 blocks x 256 thr x 16 uint4)
        const int z = bb - (CVT_BLKS + LN_BLKS);
        uint4 zero4 = {0u, 0u, 0u, 0u};
        uint4* mp = reinterpret_cast<uint4*>(mask);
#pragma unroll
        for (int i = 0; i < 16; ++i)
            mp[(size_t)z * 4096 + i * 256 + threadIdx.x] = zero4;
    }
}

// ---------------- bf16 MFMA GEMM, tile BM x BN, 2-deep pipeline --------------
// K-loop: double-buffered gload_lds staging (pre-swizzled global source chunk
// + XOR-swizzled ds_read => conflict-free), counted vmcnt (never 0 mid-loop)
// + raw s_barrier. XCD swizzle: tm = wgid % (NN/BM) (NN/BM multiple of 8).
// Epilogue: acc(+bias) bounced through LDS (stride BN+4 f32) -> contiguous
// 16B global stores (float4 / ushort8), float4 resid loads.
// EPI 0: QKV -> q (bf16, scaled)/k/v, [N][512] bf16; also folds the adjacency
//        bitmask build (atomicOr of edges + diagonal) before staging — those
//        vmem ops retire before the first counted vmcnt wait (in-order count).
// EPI 1: out_f = acc + bias + resid (f32)
// EPI 2: out_b = bf16(relu(acc + bias)), row stride 2048
template <int BM, int BN, int EPI>
__global__ __launch_bounds__(256) void gemm_swz(const unsigned short* __restrict__ A,
                                                const unsigned short* __restrict__ B,
                                                int K,
                                                const float* __restrict__ bias,
                                                const float* __restrict__ resid,
                                                float* __restrict__ out_f,
                                                unsigned short* __restrict__ out_b,
                                                unsigned short* __restrict__ q_out,
                                                unsigned short* __restrict__ k_out,
                                                unsigned short* __restrict__ v_out,
                                                const void* __restrict__ ei,
                                                uint32* __restrict__ mask, int E) {
    constexpr int MR = BM / 32;          // fragments per wave (M)
    constexpr int NR = BN / 32;          // fragments per wave (N)
    constexpr int LA = BM / 32;          // A gloads per wave per tile
    constexpr int LB = BN / 32;          // B gloads per wave per tile
    constexpr int CSTR = BN + 4;         // f32 bounce stride (16B-aligned rows)
    constexpr size_t PIPE_B = (size_t)2 * (BM + BN) * 64 * 2;
    constexpr size_t EPI_B = (size_t)BM * CSTR * 4;
    constexpr size_t LDS_B = PIPE_B > EPI_B ? PIPE_B : EPI_B;
    __shared__ __align__(16) unsigned char smem[LDS_B];
    unsigned short* a_lds = (unsigned short*)smem;
    unsigned short* b_lds = a_lds + (size_t)2 * BM * 64;
    float* c_lds = (float*)smem;

    const int tid = threadIdx.x;
    const int lane = tid & 63;
    const int wave = tid >> 6;
    const int wm = wave >> 1, wn = wave & 1;
    const int wgid = blockIdx.x;
    const int tm = wgid % (NN / BM);
    const int tn = wgid / (NN / BM);

    // ---- folded adjacency build (QKV only), before staging; self-draining ----
    if constexpr (EPI == 0) {
        if (mask) {
            const int odd = ((const int*)ei)[2 * lane + 1];
            const int is32 = (__ballot(odd != 0) != 0ull) ? 1 : 0;
            const int total = E + NN;
            for (int i = wgid * 256 + tid; i < total; i += (int)gridDim.x * 256) {
                int r, c;
                if (i < E) load_edge(ei, E, i, is32, r, c);
                else { r = i - E; c = r; }
                atomicOr(&mask[r * 128 + (c >> 5)], 1u << (c & 31));
            }
        }
    }

    f32x4 acc[MR][NR];
#pragma unroll
    for (int mi = 0; mi < MR; ++mi)
#pragma unroll
        for (int ni = 0; ni < NR; ++ni) acc[mi][ni] = (f32x4){0.f, 0.f, 0.f, 0.f};

    // staging: chunk = 1KB = 8 rows x 64 cols; lane covers row = chunk*8+l/8,
    // global col-chunk = (l&7)^(l>>3) (inverse swizzle), LDS dest linear l*16.
    const int srow = lane >> 3;
    const int sswz = ((lane & 7) ^ srow) << 3;
    const unsigned short* a_src = A + (size_t)(tm * BM + srow) * K + sswz;
    const unsigned short* b_src = B + (size_t)(tn * BN + srow) * K + sswz;

    auto stage = [&](int k0, int buf) {
        unsigned short* al = a_lds + buf * (BM * 64);
        unsigned short* bl = b_lds + buf * (BN * 64);
#pragma unroll
        for (int i = 0; i < LA; ++i) {
            const int c = wave * LA + i;
            GLOAD16(a_src + (size_t)c * 8 * K + k0, al + c * 512);
        }
#pragma unroll
        for (int i = 0; i < LB; ++i) {
            const int c = wave * LB + i;
            GLOAD16(b_src + (size_t)c * 8 * K + k0, bl + c * 512);
        }
    };

    const int NT = K >> 6;
    stage(0, 0);
    for (int t = 0; t < NT; ++t) {
        const int cur = t & 1;
        if (t + 1 < NT) {
            stage((t + 1) << 6, cur ^ 1);   // prefetch next tile
            waitcnt_vm<LA + LB>();          // oldest batch (buf[cur]) landed
        } else {
            waitcnt_vm<0>();
        }
        __builtin_amdgcn_s_barrier();       // all waves staged buf[cur]
        asm volatile("" ::: "memory");
        const unsigned short* al = a_lds + cur * (BM * 64);
        const unsigned short* bl = b_lds + cur * (BN * 64);
#pragma unroll
        for (int ks = 0; ks < 2; ++ks) {
            // fragment col-chunk, XOR-swizzled by row&7 (= lane&7, mi-uniform)
            const int cswz = (((lane >> 4) + ks * 4) ^ (lane & 7)) << 3;
            const int rl = lane & 15;
            bfrag af[MR], bfr[NR];
#pragma unroll
            for (int mi = 0; mi < MR; ++mi)
                af[mi] = *reinterpret_cast<const bfrag*>(
                    &al[(wm * (BM / 2) + mi * 16 + rl) * 64 + cswz]);
#pragma unroll
            for (int ni = 0; ni < NR; ++ni)
                bfr[ni] = *reinterpret_cast<const bfrag*>(
                    &bl[(wn * (BN / 2) + ni * 16 + rl) * 64 + cswz]);
#pragma unroll
            for (int mi = 0; mi < MR; ++mi)
#pragma unroll
                for (int ni = 0; ni < NR; ++ni)
                    acc[mi][ni] = __builtin_amdgcn_mfma_f32_16x16x32_bf16(
                        af[mi], bfr[ni], acc[mi][ni], 0, 0, 0);
        }
        asm volatile("" ::: "memory");
        __builtin_amdgcn_s_barrier();       // all waves done reading buf[cur]
    }

    // ---- epilogue: bounce acc(+bias) through LDS, contiguous 16B stores ----
    __syncthreads();                        // pipeline LDS fully consumed
    {
        const int r0 = (lane >> 4) << 2;
        const int cl = lane & 15;
        float bias_r[NR];
#pragma unroll
        for (int ni = 0; ni < NR; ++ni)
            bias_r[ni] = bias[tn * BN + wn * (BN / 2) + ni * 16 + cl];
#pragma unroll
        for (int mi = 0; mi < MR; ++mi)
#pragma unroll
            for (int ni = 0; ni < NR; ++ni) {
                const int row_l = wm * (BM / 2) + mi * 16 + r0;
                const int col_l = wn * (BN / 2) + ni * 16 + cl;
#pragma unroll
                for (int r = 0; r < 4; ++r)
                    c_lds[(size_t)(row_l + r) * CSTR + col_l] =
                        acc[mi][ni][r] + bias_r[ni];
            }
    }
    __syncthreads();

    if constexpr (EPI == 1) {               // f32 out + resid
        constexpr int IT = (BM * BN) / 1024;
#pragma unroll
        for (int it = 0; it < IT; ++it) {
            const int seg = tid + it * 256;
            const int row = seg / (BN / 4);
            const int c4 = (seg % (BN / 4)) * 4;
            f32x4 v = *reinterpret_cast<const f32x4*>(&c_lds[(size_t)row * CSTR + c4]);
            const size_t gidx = (size_t)(tm * BM + row) * 512 + tn * BN + c4;
            f32x4 rs = *reinterpret_cast<const f32x4*>(&resid[gidx]);
            *reinterpret_cast<f32x4*>(&out_f[gidx]) = v + rs;
        }
    } else {                                // bf16 out (EPI 0 or 2)
        constexpr int IT = (BM * BN) / 2048;
        unsigned short* dst;
        int cbase, stride;
        float scl = 1.f;
        if constexpr (EPI == 0) {
            const int gc0 = tn * BN;
            const int region = gc0 >> 9;    // 0=q, 1=k, 2=v (block-uniform)
            dst = region == 0 ? q_out : (region == 1 ? k_out : v_out);
            cbase = gc0 - region * 512;
            stride = 512;
            if (region == 0) scl = 0.18033688011112042f;  // 1/8 * log2(e)
        } else {
            dst = out_b;
            cbase = tn * BN;
            stride = 2048;
        }
#pragma unroll
        for (int it = 0; it < IT; ++it) {
            const int seg = tid + it * 256;
            const int row = seg / (BN / 8);
            const int c8 = (seg % (BN / 8)) * 8;
            f32x4 v0 = *reinterpret_cast<const f32x4*>(&c_lds[(size_t)row * CSTR + c8]);
            f32x4 v1 = *reinterpret_cast<const f32x4*>(&c_lds[(size_t)row * CSTR + c8 + 4]);
            ushort8v o;
            if constexpr (EPI == 0) {
#pragma unroll
                for (int i = 0; i < 4; ++i) o[i] = f2b(v0[i] * scl);
#pragma unroll
                for (int i = 0; i < 4; ++i) o[4 + i] = f2b(v1[i] * scl);
            } else {
#pragma unroll
                for (int i = 0; i < 4; ++i) o[i] = f2b(fmaxf(v0[i], 0.f));
#pragma unroll
                for (int i = 0; i < 4; ++i) o[4 + i] = f2b(fmaxf(v1[i], 0.f));
            }
            *reinterpret_cast<ushort8v*>(
                dst + (size_t)(tm * BM + row) * stride + cbase + c8) = o;
        }
    }
}

// ---------------- sparse masked attention: bitmask -> LDS compaction ---------
// wave per query; all 8 heads fused (lane = (h, t), h=lane>>3, t=lane&7).
__global__ __launch_bounds__(256) void attn_sparse(const unsigned short* __restrict__ qb,
                                                   const unsigned short* __restrict__ kb,
                                                   const unsigned short* __restrict__ vb,
                                                   const uint32* __restrict__ mask,
                                                   unsigned short* __restrict__ o_buf) {
    __shared__ int s_cols[4][1024];
    __shared__ int s_cnt[4];
    const int lane = threadIdx.x & 63;
    const int wid = threadIdx.x >> 6;
    const int q = blockIdx.x * 4 + wid;

    if (lane == 0) s_cnt[wid] = 0;
    uint32 w0 = mask[q * 128 + lane];
    uint32 w1 = mask[q * 128 + 64 + lane];
    const int base0 = lane * 32, base1 = (64 + lane) * 32;
    while (w0) {
        int b = __builtin_ctz(w0);
        w0 &= w0 - 1;
        int pos = atomicAdd(&s_cnt[wid], 1);
        s_cols[wid][pos & 1023] = base0 + b;
    }
    while (w1) {
        int b = __builtin_ctz(w1);
        w1 &= w1 - 1;
        int pos = atomicAdd(&s_cnt[wid], 1);
        s_cols[wid][pos & 1023] = base1 + b;
    }
    const int cnt = min(s_cnt[wid], 1024);   // wave-local; DS ops in-order

    ushort8v q8 = *reinterpret_cast<const ushort8v*>(qb + (size_t)q * DD + lane * 8);
    float qf[8];
#pragma unroll
    for (int i = 0; i < 8; ++i) qf[i] = b2f(q8[i]);

    float m_run = -3.0e38f, l_run = 0.f;
    float oa[8];
#pragma unroll
    for (int i = 0; i < 8; ++i) oa[i] = 0.f;

    for (int j0 = 0; j0 < cnt; j0 += 8) {
        float s_arr[8];
        int col_arr[8];
        // ---- pass 1: scores for 8 neighbors (8 independent 1KB gathers) ----
#pragma unroll
        for (int u = 0; u < 8; ++u) {
            const int idx = j0 + u;
            const bool act = idx < cnt;
            const int col = s_cols[wid][act ? idx : 0];   // uniform -> broadcast
            col_arr[u] = col;
            ushort8v kq = *reinterpret_cast<const ushort8v*>(
                kb + (size_t)col * DD + lane * 8);
            float d = qf[0] * b2f(kq[0]);
            d = fmaf(qf[1], b2f(kq[1]), d);
            d = fmaf(qf[2], b2f(kq[2]), d);
            d = fmaf(qf[3], b2f(kq[3]), d);
            d = fmaf(qf[4], b2f(kq[4]), d);
            d = fmaf(qf[5], b2f(kq[5]), d);
            d = fmaf(qf[6], b2f(kq[6]), d);
            d = fmaf(qf[7], b2f(kq[7]), d);
            // reduce across the 8 lanes of this head
            d += __shfl_xor(d, 1);
            d += __shfl_xor(d, 2);
            d += __shfl_xor(d, 4);
            s_arr[u] = act ? d : -3.0e38f;
        }
        float mloc = fmaxf(fmaxf(fmaxf(s_arr[0], s_arr[1]), fmaxf(s_arr[2], s_arr[3])),
                           fmaxf(fmaxf(s_arr[4], s_arr[5]), fmaxf(s_arr[6], s_arr[7])));
        if (mloc > m_run) {                 // defer-rescale: alpha==1 otherwise
            const float alpha = fexp2(m_run - mloc);
            l_run *= alpha;
#pragma unroll
            for (int i = 0; i < 8; ++i) oa[i] *= alpha;
            m_run = mloc;
        }
        // ---- pass 2: exp + PV (no shuffles) ----
#pragma unroll
        for (int u = 0; u < 8; ++u) {
            const float p = fexp2(s_arr[u] - m_run);  // inactive -> 0
            l_run += p;
            ushort8v vq = *reinterpret_cast<const ushort8v*>(
                vb + (size_t)col_arr[u] * DD + lane * 8);
#pragma unroll
            for (int i = 0; i < 8; ++i) oa[i] = fmaf(p, b2f(vq[i]), oa[i]);
        }
    }

    const float rl = 1.f / l_run;
    ushort8v ov;
#pragma unroll
    for (int i = 0; i < 8; ++i) ov[i] = f2b(oa[i] * rl);
    *reinterpret_cast<ushort8v*>(o_buf + (size_t)q * DD + lane * 8) = ov;
}

// ---------------- launch ----------------
extern "C" void kernel_launch(void* const* d_in, const int* in_sizes, int n_in,
                              void* d_out, int out_size, void* d_ws, size_t ws_size,
                              hipStream_t stream) {
    const float* x = (const float*)d_in[0];
    const void* ei = d_in[1];
    const float* ln1w = (const float*)d_in[2];
    const float* ln1b = (const float*)d_in[3];
    const float* w_in = (const float*)d_in[4];
    const float* b_in = (const float*)d_in[5];
    const float* w_out = (const float*)d_in[6];
    const float* b_out = (const float*)d_in[7];
    const float* ln2w = (const float*)d_in[8];
    const float* ln2b = (const float*)d_in[9];
    const float* w1 = (const float*)d_in[10];
    const float* b1 = (const float*)d_in[11];
    const float* w2 = (const float*)d_in[12];
    const float* b2 = (const float*)d_in[13];
    float* out = (float*)d_out;
    const int E = in_sizes[1] / 2;

    char* ws = (char*)d_ws;
    size_t off = 0;
    auto alloc = [&](size_t bytes) -> void* {
        void* p = ws + off;
        off = (off + bytes + 255) & ~(size_t)255;
        return p;
    };
    uint32* mask1 = (uint32*)alloc((size_t)NN * 128 * 4);   // 2 MiB
    unsigned short* w_in_b = (unsigned short*)alloc((size_t)1536 * 512 * 2);
    unsigned short* w_out_b = (unsigned short*)alloc((size_t)512 * 512 * 2);
    unsigned short* w1_b = (unsigned short*)alloc((size_t)2048 * 512 * 2);
    unsigned short* w2_b = (unsigned short*)alloc((size_t)512 * 2048 * 2);
    unsigned short* xn = (unsigned short*)alloc((size_t)NN * DD * 2);
    unsigned short* q_b = (unsigned short*)alloc((size_t)NN * DD * 2); // 4 MiB
    unsigned short* k_b = (unsigned short*)alloc((size_t)NN * DD * 2); // 4 MiB
    unsigned short* v_b = (unsigned short*)alloc((size_t)NN * DD * 2); // 4 MiB
    unsigned short* o_buf = (unsigned short*)alloc((size_t)NN * DD * 2); // 4 MiB
    float* x1 = (float*)alloc((size_t)NN * DD * 4);
    unsigned short* xm = (unsigned short*)alloc((size_t)NN * DD * 2);
    // MLP hidden [4096][2048] bf16 (16 MiB) aliases q_b+k_b+v_b+o_buf
    // (all dead after out-proj; sizes are 256B-aligned so the span is exact)
    unsigned short* h_buf = q_b;

    // D1: prologue — weight cvt + LN1 (wave/row) + mask zero
    prologue<<<CVT_BLKS + LN_BLKS + ZERO_BLKS, 256, 0, stream>>>(
        w_in, w_out, w1, w2, w_in_b, w_out_b, w1_b, w2_b,
        x, ln1w, ln1b, xn, mask1);

    // D2: QKV GEMM (128x64, grid 768, 3 blocks/CU) + folded adjacency build
    gemm_swz<128, 64, 0><<<32 * 24, 256, 0, stream>>>(
        xn, w_in_b, 512, b_in, nullptr, nullptr, nullptr, q_b, k_b, v_b,
        ei, mask1, E);

    // D3: attention
    attn_sparse<<<NN / 4, 256, 0, stream>>>(q_b, k_b, v_b, mask1, o_buf);

    // D4: out-proj (64x64, grid 512): x1 = x + o @ w_out^T + b_out
    gemm_swz<64, 64, 1><<<64 * 8, 256, 0, stream>>>(
        o_buf, w_out_b, 512, b_out, x, x1, nullptr, nullptr, nullptr, nullptr,
        nullptr, nullptr, 0);

    // D5: LN2
    ln_rows<<<NN / 4, 256, 0, stream>>>(x1, ln2w, ln2b, xm);

    // D6: MLP1 (128x128, grid 512): h = bf16(relu(xm @ w1^T + b1))
    gemm_swz<128, 128, 2><<<32 * 16, 256, 0, stream>>>(
        xm, w1_b, 512, b1, nullptr, nullptr, h_buf, nullptr, nullptr, nullptr,
        nullptr, nullptr, 0);

    // D7: MLP2 (64x64, grid 512): out = x1 + h @ w2^T + b2
    gemm_swz<64, 64, 1><<<64 * 8, 256, 0, stream>>>(
        h_buf, w2_b, 2048, b2, x1, out, nullptr, nullptr, nullptr, nullptr,
        nullptr, nullptr, 0);
}